// Round 5
// baseline (208.296 us; speedup 1.0000x reference)
//
#include <hip/hip_runtime.h>
#include <hip/hip_bf16.h>

#define C 64   // C_IN == C_OUT == 64

typedef unsigned short u16;
typedef unsigned int u32;
typedef unsigned long long u64;

__device__ __forceinline__ u16 f2bf_rne(float v) {
    unsigned u = __float_as_uint(v);
    u += 0x7FFFu + ((u >> 16) & 1u);
    return (u16)(u >> 16);
}
__device__ __forceinline__ float bf2f(u16 u) {
    return __uint_as_float((unsigned)u << 16);
}

// ============================================================================
// Atomic-free CSR build: MSD bucket sort by row>>8 (256 buckets), then
// per-bucket counting sort by row&255. No global atomics in the hot path.
// ============================================================================

// --- P1 hist: per-block 256-bin LDS histogram of row>>8; fused x->bf16;
// zeroes the scanAB done-ticket. ---
__global__ __launch_bounds__(256) void p1hist_kernel(const int* __restrict__ row,
                                                     u32* __restrict__ hoff,  // [NB][256]
                                                     const float* __restrict__ x,
                                                     u16* __restrict__ xh,
                                                     u32* __restrict__ done,
                                                     int E, int NB, int total4, int nthreads) {
    __shared__ u32 h[256];
    int t = threadIdx.x;
    int b = blockIdx.x;
    if (b == 0 && t == 0) *done = 0;
    h[t] = 0;
    __syncthreads();
    int base = b * 1024;
#pragma unroll
    for (int u = 0; u < 4; u++) {
        int e = base + u * 256 + t;
        if (e < E) {
            int r = row[e];
            atomicAdd(&h[r >> 8], 1u);
        }
    }
    __syncthreads();
    hoff[(size_t)b * 256 + t] = h[t];   // block-major, coalesced

    // fused x -> bf16 convert (grid-stride)
    int gtid = b * 256 + t;
    for (int i = gtid; i < total4; i += nthreads) {
        float4 v = *(const float4*)(x + (size_t)i * 4);
        ushort4 o;
        o.x = f2bf_rne(v.x); o.y = f2bf_rne(v.y);
        o.z = f2bf_rne(v.z); o.w = f2bf_rne(v.w);
        *(ushort4*)(xh + (size_t)i * 4) = o;
    }
}

// --- scanAB (fused): block d scans hoff[.][d] over blocks (exclusive,
// in-place), T[d] = total. Last block (device ticket) scans T -> Tpre. ---
__global__ __launch_bounds__(256) void scanAB_kernel(u32* __restrict__ hoff,
                                                     u32* __restrict__ T,
                                                     u32* __restrict__ Tpre,
                                                     int* __restrict__ rowptr,
                                                     u32* __restrict__ done,
                                                     int N, int NB) {
    __shared__ u32 s[256];
    __shared__ u32 lastFlag;
    int t = threadIdx.x;
    int d = blockIdx.x;
    u32 carry = 0;
    int nchunk = (NB + 255) / 256;
    for (int ch = 0; ch < nchunk; ch++) {
        int idx = ch * 256 + t;
        u32 v = (idx < NB) ? hoff[(size_t)idx * 256 + d] : 0;
        s[t] = v;
        __syncthreads();
        for (int off = 1; off < 256; off <<= 1) {
            u32 u = (t >= off) ? s[t - off] : 0;
            __syncthreads();
            s[t] += u;
            __syncthreads();
        }
        if (idx < NB) hoff[(size_t)idx * 256 + d] = carry + s[t] - v;  // exclusive
        u32 tot = s[255];
        __syncthreads();
        carry += tot;
    }
    if (t == 0) T[d] = carry;
    __threadfence();                      // release T[d]
    if (t == 0) {
        u32 tk = atomicAdd(done, 1u);
        lastFlag = (tk == 255u) ? 1u : 0u;
    }
    __syncthreads();
    if (lastFlag) {
        __threadfence();                  // acquire all T[]
        u32 v = T[t];
        s[t] = v;
        __syncthreads();
        for (int off = 1; off < 256; off <<= 1) {
            u32 u = (t >= off) ? s[t - off] : 0;
            __syncthreads();
            s[t] += u;
            __syncthreads();
        }
        Tpre[t] = s[t] - v;
        if (t == 255) {
            Tpre[256] = s[255];
            rowptr[N] = (int)s[255];
        }
    }
}

// --- P1 scatter: place edges into their row>>8 bucket. Within-bucket order
// arbitrary (LDS returning atomics) — legal for an MSD pass. Payload packs
// (row<<16)|col in high 32 bits, ew bits in low 32. ---
__global__ __launch_bounds__(256) void p1scatter_kernel(const int* __restrict__ row,
                                                        const int* __restrict__ col,
                                                        const float* __restrict__ ew,
                                                        const u32* __restrict__ hoff, // [NB][256] excl
                                                        const u32* __restrict__ Tpre,
                                                        u64* __restrict__ pay,
                                                        int E) {
    __shared__ u32 cur[256];
    int t = threadIdx.x;
    int b = blockIdx.x;
    cur[t] = Tpre[t] + hoff[(size_t)b * 256 + t];
    __syncthreads();
    int base = b * 1024;
#pragma unroll
    for (int u = 0; u < 4; u++) {
        int e = base + u * 256 + t;
        if (e < E) {
            u32 r = (u32)row[e];
            u32 c = (u32)col[e];
            u32 rc = (r << 16) | c;
            u32 pos = atomicAdd(&cur[r >> 8], 1u);
            pay[pos] = ((u64)rc << 32) | (u64)__float_as_uint(ew[e]);
        }
    }
}

// --- P2: per-bucket counting sort by row&255 into final CSR; writes rowptr
// for this bucket's 256 rows, deg sums (LDS f32 atomics) -> dis.
// ewc stores (raw ew, pure col); normalization is recomputed in the SpMMs. ---
__global__ __launch_bounds__(256) void p2_kernel(const u64* __restrict__ pay,
                                                 const u32* __restrict__ Tpre,
                                                 int* __restrict__ rowptr,
                                                 float* __restrict__ dis,
                                                 float2* __restrict__ ewc,
                                                 int N) {
    __shared__ u32 h[256];
    __shared__ u32 s[256];
    __shared__ u32 cur[256];
    __shared__ float dsum[256];
    int t = threadIdx.x;
    int bk = blockIdx.x;
    u32 base = Tpre[bk];
    u32 cnt = Tpre[bk + 1] - base;

    h[t] = 0;
    dsum[t] = 0.0f;
    __syncthreads();
    for (u32 j = t; j < cnt; j += 256) {
        u64 v = pay[base + j];
        u32 lr = (u32)(v >> 48) & 255u;   // row & 255 (row>>8 == bk here)
        atomicAdd(&h[lr], 1u);
    }
    __syncthreads();
    // exclusive scan of h
    u32 hv = h[t];
    s[t] = hv;
    __syncthreads();
    for (int off = 1; off < 256; off <<= 1) {
        u32 u = (t >= off) ? s[t - off] : 0;
        __syncthreads();
        s[t] += u;
        __syncthreads();
    }
    u32 p = s[t] - hv;   // exclusive
    int r = bk * 256 + t;
    if (r < N) rowptr[r] = (int)(base + p);
    cur[t] = base + p;
    __syncthreads();
    for (u32 j = t; j < cnt; j += 256) {
        u64 v = pay[base + j];
        u32 rc = (u32)(v >> 32);
        u32 lr = (rc >> 16) & 255u;
        float w = __uint_as_float((u32)v);
        u32 pos = atomicAdd(&cur[lr], 1u);
        ewc[pos] = make_float2(w, __uint_as_float(rc & 0xffffu));  // raw ew, pure col
        atomicAdd(&dsum[lr], w);
    }
    __syncthreads();
    if (r < N) {
        float dv = dsum[t];
        dis[r] = (dv > 0.0f) ? rsqrtf(dv) : 0.0f;
    }
}

// ============================================================================
// SpMM pass 1: T1 = L_hat @ x. Half-wave per row (2 rows/wave), u64 gathers,
// LDS edge staging, norm recomputed on the fly (no ewc writeback).
// 4 gathers in flight per j-iteration.
// ============================================================================
__global__ __launch_bounds__(256) void spmm_t1_kernel(
        const int* __restrict__ rowptr,
        const float2* __restrict__ ewc,
        const float* __restrict__ dis,
        const u64* __restrict__ h64,        // bf16 [N][64] viewed as [N][16] u64
        float* __restrict__ out32,          // fp32 [N][C]
        u64* __restrict__ outbf,            // bf16 [N][64] viewed as [N][16] u64
        int N) {
    __shared__ float2 eds[8][32];           // per half-wave staging (2 KB)

    int tid  = threadIdx.x;
    int hw   = tid >> 5;                    // half-wave slot in block 0..7
    int l32  = tid & 31;                    // lane within half
    int e2   = l32 >> 4;                    // edge selector within pair
    int cq   = l32 & 15;                    // channel quad (4 bf16 via u64)

    int row = blockIdx.x * 8 + hw;
    if (row >= N) return;

    int beg = rowptr[row];
    int end = rowptr[row + 1];
    float disr = dis[row];

    float a0 = 0.f, a1 = 0.f, a2 = 0.f, a3 = 0.f;

    for (int base = beg; base < end; base += 32) {
        int idx = base + l32;
        bool valid = idx < end;
        // zero-pad: w=0, col=0 -> harmless gather of row 0
        float2 ed = valid ? ewc[idx] : make_float2(0.0f, __uint_as_float(0));
        u32 c = __float_as_uint(ed.y);
        float wv = -disr * ed.x * dis[c];
        eds[hw][l32] = make_float2(wv, ed.y);
        int cnt = end - base; if (cnt > 32) cnt = 32;
        int cnt8 = (cnt + 7) & ~7;          // padded slots are zeros
        for (int j = 0; j < cnt8; j += 8) {
            float2 f0 = eds[hw][j + e2];
            float2 f1 = eds[hw][j + 2 + e2];
            float2 f2 = eds[hw][j + 4 + e2];
            float2 f3 = eds[hw][j + 6 + e2];
            u64 hv0 = h64[(size_t)__float_as_uint(f0.y) * 16 + cq];
            u64 hv1 = h64[(size_t)__float_as_uint(f1.y) * 16 + cq];
            u64 hv2 = h64[(size_t)__float_as_uint(f2.y) * 16 + cq];
            u64 hv3 = h64[(size_t)__float_as_uint(f3.y) * 16 + cq];
            float w0 = f0.x, w1 = f1.x, w2 = f2.x, w3 = f3.x;
            u32 lo, hi;
            lo = (u32)hv0; hi = (u32)(hv0 >> 32);
            a0 = fmaf(w0, bf2f((u16)(lo & 0xffffu)), a0);
            a1 = fmaf(w0, bf2f((u16)(lo >> 16)),     a1);
            a2 = fmaf(w0, bf2f((u16)(hi & 0xffffu)), a2);
            a3 = fmaf(w0, bf2f((u16)(hi >> 16)),     a3);
            lo = (u32)hv1; hi = (u32)(hv1 >> 32);
            a0 = fmaf(w1, bf2f((u16)(lo & 0xffffu)), a0);
            a1 = fmaf(w1, bf2f((u16)(lo >> 16)),     a1);
            a2 = fmaf(w1, bf2f((u16)(hi & 0xffffu)), a2);
            a3 = fmaf(w1, bf2f((u16)(hi >> 16)),     a3);
            lo = (u32)hv2; hi = (u32)(hv2 >> 32);
            a0 = fmaf(w2, bf2f((u16)(lo & 0xffffu)), a0);
            a1 = fmaf(w2, bf2f((u16)(lo >> 16)),     a1);
            a2 = fmaf(w2, bf2f((u16)(hi & 0xffffu)), a2);
            a3 = fmaf(w2, bf2f((u16)(hi >> 16)),     a3);
            lo = (u32)hv3; hi = (u32)(hv3 >> 32);
            a0 = fmaf(w3, bf2f((u16)(lo & 0xffffu)), a0);
            a1 = fmaf(w3, bf2f((u16)(lo >> 16)),     a1);
            a2 = fmaf(w3, bf2f((u16)(hi & 0xffffu)), a2);
            a3 = fmaf(w3, bf2f((u16)(hi >> 16)),     a3);
        }
    }

    // combine the two edge-halves (partner lane = l32 ^ 16)
    a0 += __shfl_xor(a0, 16);
    a1 += __shfl_xor(a1, 16);
    a2 += __shfl_xor(a2, 16);
    a3 += __shfl_xor(a3, 16);

    if (e2 == 0) {
        *(float4*)(out32 + (size_t)row * C + 4 * cq) = make_float4(a0, a1, a2, a3);
        u32 p0 = (u32)f2bf_rne(a0) | ((u32)f2bf_rne(a1) << 16);
        u32 p1 = (u32)f2bf_rne(a2) | ((u32)f2bf_rne(a3) << 16);
        outbf[(size_t)row * 16 + cq] = (u64)p0 | ((u64)p1 << 32);
    }
}

// ============================================================================
// Fused SpMM pass 2 + dense epilogue. Block = 64 rows.
// Phase A: quarter-wave (16 lanes) per row x 4 sequential rows: P = L_hat@T1h,
//          T2 = 2P - x written to LDS (no global round-trip).
// Phase B: register-tiled GEMM out = relu([x | T1 | T2] @ Wcat + b),
//          s>=8 slabs read from T2s LDS (broadcast, conflict-free).
// ============================================================================
__global__ __launch_bounds__(256) void spmm_gemm_kernel(
        const int* __restrict__ rowptr,
        const float2* __restrict__ ewc,
        const float* __restrict__ dis,
        const u64* __restrict__ t1h,       // bf16 [N][64] viewed as [N][16] u64
        const float* __restrict__ x,
        const float* __restrict__ T1,
        const float* __restrict__ W,       // [192][64] row-major
        const float* __restrict__ b,
        float* __restrict__ out, int N) {
    __shared__ float T2s[64][68];          // +4 pad: conflict-free column reads
    __shared__ float As[16][64];
    __shared__ float Ws[16][64];
    __shared__ float2 eds[16][16];

    int t  = threadIdx.x;
    int q  = t >> 4;                       // quarter-wave 0..15
    int cq = t & 15;                       // channel quad
    int n0 = blockIdx.x * 64;

    // ---- Phase A: SpMM + Chebyshev combine into LDS ----
    for (int rr = 0; rr < 4; rr++) {
        int row = n0 + q * 4 + rr;
        if (row < N) {
            int beg = rowptr[row];
            int end = rowptr[row + 1];
            float disr = dis[row];
            float a0 = 0.f, a1 = 0.f, a2 = 0.f, a3 = 0.f;
            for (int base = beg; base < end; base += 16) {
                int idx = base + cq;
                float2 ed = (idx < end) ? ewc[idx] : make_float2(0.0f, __uint_as_float(0));
                u32 c = __float_as_uint(ed.y);
                float wv = -disr * ed.x * dis[c];
                eds[q][cq] = make_float2(wv, ed.y);
                int cnt = end - base; if (cnt > 16) cnt = 16;
                int cnt4 = (cnt + 3) & ~3;     // padded slots are zeros
                for (int j = 0; j < cnt4; j += 4) {
                    float2 f0 = eds[q][j];
                    float2 f1 = eds[q][j + 1];
                    float2 f2 = eds[q][j + 2];
                    float2 f3 = eds[q][j + 3];
                    u64 h0 = t1h[(size_t)__float_as_uint(f0.y) * 16 + cq];
                    u64 h1 = t1h[(size_t)__float_as_uint(f1.y) * 16 + cq];
                    u64 h2 = t1h[(size_t)__float_as_uint(f2.y) * 16 + cq];
                    u64 h3 = t1h[(size_t)__float_as_uint(f3.y) * 16 + cq];
                    u32 lo, hi;
                    lo = (u32)h0; hi = (u32)(h0 >> 32);
                    a0 = fmaf(f0.x, bf2f((u16)(lo & 0xffffu)), a0);
                    a1 = fmaf(f0.x, bf2f((u16)(lo >> 16)),     a1);
                    a2 = fmaf(f0.x, bf2f((u16)(hi & 0xffffu)), a2);
                    a3 = fmaf(f0.x, bf2f((u16)(hi >> 16)),     a3);
                    lo = (u32)h1; hi = (u32)(h1 >> 32);
                    a0 = fmaf(f1.x, bf2f((u16)(lo & 0xffffu)), a0);
                    a1 = fmaf(f1.x, bf2f((u16)(lo >> 16)),     a1);
                    a2 = fmaf(f1.x, bf2f((u16)(hi & 0xffffu)), a2);
                    a3 = fmaf(f1.x, bf2f((u16)(hi >> 16)),     a3);
                    lo = (u32)h2; hi = (u32)(h2 >> 32);
                    a0 = fmaf(f2.x, bf2f((u16)(lo & 0xffffu)), a0);
                    a1 = fmaf(f2.x, bf2f((u16)(lo >> 16)),     a1);
                    a2 = fmaf(f2.x, bf2f((u16)(hi & 0xffffu)), a2);
                    a3 = fmaf(f2.x, bf2f((u16)(hi >> 16)),     a3);
                    lo = (u32)h3; hi = (u32)(h3 >> 32);
                    a0 = fmaf(f3.x, bf2f((u16)(lo & 0xffffu)), a0);
                    a1 = fmaf(f3.x, bf2f((u16)(lo >> 16)),     a1);
                    a2 = fmaf(f3.x, bf2f((u16)(hi & 0xffffu)), a2);
                    a3 = fmaf(f3.x, bf2f((u16)(hi >> 16)),     a3);
                }
            }
            float4 xv = *(const float4*)(x + (size_t)row * C + 4 * cq);
            *(float4*)&T2s[q * 4 + rr][4 * cq] =
                make_float4(2.f * a0 - xv.x, 2.f * a1 - xv.y,
                            2.f * a2 - xv.z, 2.f * a3 - xv.w);
        }
    }
    // first __syncthreads in the s-loop orders T2s writes before any T2s read

    // ---- Phase B: GEMM ----
    int tx = t & 15;
    int ty = t >> 4;
    int sn = t >> 2;
    int skb = (t & 3) * 4;

    float acc[4][4];
#pragma unroll
    for (int i = 0; i < 4; i++)
#pragma unroll
        for (int j = 0; j < 4; j++) acc[i][j] = 0.0f;

#pragma unroll 1
    for (int s = 0; s < 12; s++) {
        float4 wv = *(const float4*)(W + s * 1024 + t * 4);
        float4 av = make_float4(0.f, 0.f, 0.f, 0.f);
        int nn = n0 + sn;
        if (s < 8 && nn < N) {
            const float* src = (s < 4) ? x : T1;
            av = *(const float4*)(src + (size_t)nn * C + (s & 3) * 16 + skb);
        }
        __syncthreads();
        {
            int wk = (t * 4) >> 6;
            int wc = (t * 4) & 63;
            *(float4*)&Ws[wk][wc] = wv;
        }
        if (s < 8) {
            As[skb + 0][sn] = av.x;
            As[skb + 1][sn] = av.y;
            As[skb + 2][sn] = av.z;
            As[skb + 3][sn] = av.w;
        }
        __syncthreads();

        if (s < 8) {
#pragma unroll
            for (int kk = 0; kk < 16; kk++) {
                float4 a4 = *(const float4*)&As[kk][ty * 4];
                float4 w4 = *(const float4*)&Ws[kk][tx * 4];
                float ar[4] = {a4.x, a4.y, a4.z, a4.w};
                float wr[4] = {w4.x, w4.y, w4.z, w4.w};
#pragma unroll
                for (int i = 0; i < 4; i++)
#pragma unroll
                    for (int j = 0; j < 4; j++)
                        acc[i][j] = fmaf(ar[i], wr[j], acc[i][j]);
            }
        } else {
            int ks = (s - 8) * 16;
#pragma unroll
            for (int kk = 0; kk < 16; kk++) {
                float4 w4 = *(const float4*)&Ws[kk][tx * 4];
                float wr[4] = {w4.x, w4.y, w4.z, w4.w};
                float ar[4];
#pragma unroll
                for (int i = 0; i < 4; i++) ar[i] = T2s[ty * 4 + i][ks + kk];
#pragma unroll
                for (int i = 0; i < 4; i++)
#pragma unroll
                    for (int j = 0; j < 4; j++)
                        acc[i][j] = fmaf(ar[i], wr[j], acc[i][j]);
            }
        }
    }

    float4 bv = *(const float4*)(b + tx * 4);
    float br[4] = {bv.x, bv.y, bv.z, bv.w};
#pragma unroll
    for (int i = 0; i < 4; i++) {
        int node = n0 + ty * 4 + i;
        if (node < N) {
            float4 o;
            o.x = fmaxf(acc[i][0] + br[0], 0.0f);
            o.y = fmaxf(acc[i][1] + br[1], 0.0f);
            o.z = fmaxf(acc[i][2] + br[2], 0.0f);
            o.w = fmaxf(acc[i][3] + br[3], 0.0f);
            *(float4*)(out + (size_t)node * C + tx * 4) = o;
        }
    }
}

extern "C" void kernel_launch(void* const* d_in, const int* in_sizes, int n_in,
                              void* d_out, int out_size, void* d_ws, size_t ws_size,
                              hipStream_t stream) {
    const float* x  = (const float*)d_in[0];
    const int*   ei = (const int*)d_in[1];
    const float* ew = (const float*)d_in[2];
    const float* W  = (const float*)d_in[3];
    const float* b  = (const float*)d_in[4];
    float* out = (float*)d_out;

    const int N = in_sizes[0] / C;
    const int E = in_sizes[2];
    const int* row = ei;        // edge_index[0]
    const int* col = ei + E;    // edge_index[1]

    char* ws = (char*)d_ws;
    size_t off = 0;
    auto alloc = [&](size_t bytes) {
        void* p = ws + off;
        off = (off + bytes + 255) & ~(size_t)255;
        return p;
    };
    const int NB = (E + 1023) / 1024;        // histogram/partition blocks
    const int NBUCK = (N + 255) / 256;       // row buckets (196)

    float*  dis    = (float*)alloc((size_t)N * 4);
    int*    rowptr = (int*)alloc((size_t)(N + 1) * 4);
    float2* ewc    = (float2*)alloc((size_t)E * 8);
    u64*    pay    = (u64*)alloc((size_t)E * 8);
    float*  T1     = (float*)alloc((size_t)N * C * 4);
    u32*    hoff   = (u32*)alloc((size_t)NB * 256 * 4);
    u32*    T      = (u32*)alloc((size_t)256 * 4);
    u32*    Tpre   = (u32*)alloc((size_t)257 * 4);
    u32*    done   = (u32*)alloc((size_t)256);
    u16*    xh     = (u16*)alloc((size_t)N * C * 2);
    u16*    T1h    = (u16*)alloc((size_t)N * C * 2);

    const int B = 256;
    int total4 = N * C / 4;

    p1hist_kernel<<<NB, B, 0, stream>>>(row, hoff, x, xh, done, E, NB, total4, NB * B);
    scanAB_kernel<<<256, B, 0, stream>>>(hoff, T, Tpre, rowptr, done, N, NB);
    p1scatter_kernel<<<NB, B, 0, stream>>>(row, col, ew, hoff, Tpre, pay, E);
    p2_kernel<<<NBUCK, B, 0, stream>>>(pay, Tpre, rowptr, dis, ewc, N);

    int spmm_blocks = (N + 7) / 8;           // 8 rows per block (half-wave per row)
    spmm_t1_kernel<<<spmm_blocks, B, 0, stream>>>(rowptr, ewc, dis, (const u64*)xh,
                                                  T1, (u64*)T1h, N);
    spmm_gemm_kernel<<<(N + 63) / 64, B, 0, stream>>>(rowptr, ewc, dis, (const u64*)T1h,
                                                      x, T1, W, b, out, N);
}

// Round 6
// 190.011 us; speedup vs baseline: 1.0962x; 1.0962x over previous
//
#include <hip/hip_runtime.h>
#include <hip/hip_bf16.h>

#define C 64   // C_IN == C_OUT == 64

typedef unsigned short u16;
typedef unsigned int u32;
typedef unsigned long long u64;

__device__ __forceinline__ u16 f2bf_rne(float v) {
    unsigned u = __float_as_uint(v);
    u += 0x7FFFu + ((u >> 16) & 1u);
    return (u16)(u >> 16);
}
__device__ __forceinline__ float bf2f(u16 u) {
    return __uint_as_float((unsigned)u << 16);
}

// ============================================================================
// Atomic-free CSR build: MSD bucket sort by row>>8 (256 buckets), then
// per-bucket counting sort by row&255. No global atomics in the hot path.
// ============================================================================

// --- P1 hist: per-block 256-bin LDS histogram of row>>8; fused x->bf16;
// zeroes the scanAB done-ticket. ---
__global__ __launch_bounds__(256) void p1hist_kernel(const int* __restrict__ row,
                                                     u32* __restrict__ hoff,  // [NB][256]
                                                     const float* __restrict__ x,
                                                     u16* __restrict__ xh,
                                                     u32* __restrict__ done,
                                                     int E, int NB, int total4, int nthreads) {
    __shared__ u32 h[256];
    int t = threadIdx.x;
    int b = blockIdx.x;
    if (b == 0 && t == 0) *done = 0;
    h[t] = 0;
    __syncthreads();
    int base = b * 1024;
#pragma unroll
    for (int u = 0; u < 4; u++) {
        int e = base + u * 256 + t;
        if (e < E) {
            int r = row[e];
            atomicAdd(&h[r >> 8], 1u);
        }
    }
    __syncthreads();
    hoff[(size_t)b * 256 + t] = h[t];   // block-major, coalesced

    // fused x -> bf16 convert (grid-stride)
    int gtid = b * 256 + t;
    for (int i = gtid; i < total4; i += nthreads) {
        float4 v = *(const float4*)(x + (size_t)i * 4);
        ushort4 o;
        o.x = f2bf_rne(v.x); o.y = f2bf_rne(v.y);
        o.z = f2bf_rne(v.z); o.w = f2bf_rne(v.w);
        *(ushort4*)(xh + (size_t)i * 4) = o;
    }
}

// --- scanAB (fused): block d scans hoff[.][d] over blocks (exclusive,
// in-place), T[d] = total. Last block (device ticket) scans T -> Tpre. ---
__global__ __launch_bounds__(256) void scanAB_kernel(u32* __restrict__ hoff,
                                                     u32* __restrict__ T,
                                                     u32* __restrict__ Tpre,
                                                     int* __restrict__ rowptr,
                                                     u32* __restrict__ done,
                                                     int N, int NB) {
    __shared__ u32 s[256];
    __shared__ u32 lastFlag;
    int t = threadIdx.x;
    int d = blockIdx.x;
    u32 carry = 0;
    int nchunk = (NB + 255) / 256;
    for (int ch = 0; ch < nchunk; ch++) {
        int idx = ch * 256 + t;
        u32 v = (idx < NB) ? hoff[(size_t)idx * 256 + d] : 0;
        s[t] = v;
        __syncthreads();
        for (int off = 1; off < 256; off <<= 1) {
            u32 u = (t >= off) ? s[t - off] : 0;
            __syncthreads();
            s[t] += u;
            __syncthreads();
        }
        if (idx < NB) hoff[(size_t)idx * 256 + d] = carry + s[t] - v;  // exclusive
        u32 tot = s[255];
        __syncthreads();
        carry += tot;
    }
    if (t == 0) T[d] = carry;
    __threadfence();                      // release T[d]
    if (t == 0) {
        u32 tk = atomicAdd(done, 1u);
        lastFlag = (tk == 255u) ? 1u : 0u;
    }
    __syncthreads();
    if (lastFlag) {
        __threadfence();                  // acquire all T[]
        u32 v = T[t];
        s[t] = v;
        __syncthreads();
        for (int off = 1; off < 256; off <<= 1) {
            u32 u = (t >= off) ? s[t - off] : 0;
            __syncthreads();
            s[t] += u;
            __syncthreads();
        }
        Tpre[t] = s[t] - v;
        if (t == 255) {
            Tpre[256] = s[255];
            rowptr[N] = (int)s[255];
        }
    }
}

// --- P1 scatter: place edges into their row>>8 bucket. Within-bucket order
// arbitrary (LDS returning atomics) — legal for an MSD pass. Payload packs
// (row<<16)|col in high 32 bits, ew bits in low 32. ---
__global__ __launch_bounds__(256) void p1scatter_kernel(const int* __restrict__ row,
                                                        const int* __restrict__ col,
                                                        const float* __restrict__ ew,
                                                        const u32* __restrict__ hoff, // [NB][256] excl
                                                        const u32* __restrict__ Tpre,
                                                        u64* __restrict__ pay,
                                                        int E) {
    __shared__ u32 cur[256];
    int t = threadIdx.x;
    int b = blockIdx.x;
    cur[t] = Tpre[t] + hoff[(size_t)b * 256 + t];
    __syncthreads();
    int base = b * 1024;
#pragma unroll
    for (int u = 0; u < 4; u++) {
        int e = base + u * 256 + t;
        if (e < E) {
            u32 r = (u32)row[e];
            u32 c = (u32)col[e];
            u32 rc = (r << 16) | c;
            u32 pos = atomicAdd(&cur[r >> 8], 1u);
            pay[pos] = ((u64)rc << 32) | (u64)__float_as_uint(ew[e]);
        }
    }
}

// --- P2: per-bucket counting sort by row&255 into final CSR; writes rowptr
// for this bucket's 256 rows, deg sums (LDS f32 atomics) -> dis.
// ewc stores (raw ew, pure col); normalization is recomputed in the SpMMs. ---
__global__ __launch_bounds__(256) void p2_kernel(const u64* __restrict__ pay,
                                                 const u32* __restrict__ Tpre,
                                                 int* __restrict__ rowptr,
                                                 float* __restrict__ dis,
                                                 float2* __restrict__ ewc,
                                                 int N) {
    __shared__ u32 h[256];
    __shared__ u32 s[256];
    __shared__ u32 cur[256];
    __shared__ float dsum[256];
    int t = threadIdx.x;
    int bk = blockIdx.x;
    u32 base = Tpre[bk];
    u32 cnt = Tpre[bk + 1] - base;

    h[t] = 0;
    dsum[t] = 0.0f;
    __syncthreads();
    for (u32 j = t; j < cnt; j += 256) {
        u64 v = pay[base + j];
        u32 lr = (u32)(v >> 48) & 255u;   // row & 255 (row>>8 == bk here)
        atomicAdd(&h[lr], 1u);
    }
    __syncthreads();
    // exclusive scan of h
    u32 hv = h[t];
    s[t] = hv;
    __syncthreads();
    for (int off = 1; off < 256; off <<= 1) {
        u32 u = (t >= off) ? s[t - off] : 0;
        __syncthreads();
        s[t] += u;
        __syncthreads();
    }
    u32 p = s[t] - hv;   // exclusive
    int r = bk * 256 + t;
    if (r < N) rowptr[r] = (int)(base + p);
    cur[t] = base + p;
    __syncthreads();
    for (u32 j = t; j < cnt; j += 256) {
        u64 v = pay[base + j];
        u32 rc = (u32)(v >> 32);
        u32 lr = (rc >> 16) & 255u;
        float w = __uint_as_float((u32)v);
        u32 pos = atomicAdd(&cur[lr], 1u);
        ewc[pos] = make_float2(w, __uint_as_float(rc & 0xffffu));  // raw ew, pure col
        atomicAdd(&dsum[lr], w);
    }
    __syncthreads();
    if (r < N) {
        float dv = dsum[t];
        dis[r] = (dv > 0.0f) ? rsqrtf(dv) : 0.0f;
    }
}

// ============================================================================
// CSR SpMM: half-wave per row (2 rows/wave), u64 (4-channel) gathers, LDS
// edge staging, norm recomputed on the fly (identical fp32 expr both passes).
// WBF=1 additionally writes the bf16-packed output (needed after pass 1 only).
// High grid (N/8 blocks) — gather latency hidden by TLP (r5 lesson).
// ============================================================================
template <int WBF>
__global__ __launch_bounds__(256) void spmm_kernel(
        const int* __restrict__ rowptr,
        const float2* __restrict__ ewc,
        const float* __restrict__ dis,
        const u64* __restrict__ h64,        // bf16 [N][64] viewed as [N][16] u64
        float* __restrict__ out32,          // fp32 [N][C]
        u64* __restrict__ outbf,            // bf16 [N][64] viewed as [N][16] u64
        int N) {
    __shared__ float2 eds[8][32];           // per half-wave staging (2 KB)

    int tid  = threadIdx.x;
    int hw   = tid >> 5;                    // half-wave slot in block 0..7
    int l32  = tid & 31;                    // lane within half
    int e2   = l32 >> 4;                    // edge selector within pair
    int cq   = l32 & 15;                    // channel quad (4 bf16 via u64)

    int row = blockIdx.x * 8 + hw;
    if (row >= N) return;

    int beg = rowptr[row];
    int end = rowptr[row + 1];
    float disr = dis[row];

    float a0 = 0.f, a1 = 0.f, a2 = 0.f, a3 = 0.f;

    for (int base = beg; base < end; base += 32) {
        int idx = base + l32;
        bool valid = idx < end;
        // zero-pad: w=0, col=0 -> harmless gather of row 0
        float2 ed = valid ? ewc[idx] : make_float2(0.0f, __uint_as_float(0));
        u32 c = __float_as_uint(ed.y);
        float wv = -disr * ed.x * dis[c];
        eds[hw][l32] = make_float2(wv, ed.y);
        int cnt = end - base; if (cnt > 32) cnt = 32;
        int cnt8 = (cnt + 7) & ~7;          // padded slots are zeros
        for (int j = 0; j < cnt8; j += 8) {
            float2 f0 = eds[hw][j + e2];
            float2 f1 = eds[hw][j + 2 + e2];
            float2 f2 = eds[hw][j + 4 + e2];
            float2 f3 = eds[hw][j + 6 + e2];
            u64 hv0 = h64[(size_t)__float_as_uint(f0.y) * 16 + cq];
            u64 hv1 = h64[(size_t)__float_as_uint(f1.y) * 16 + cq];
            u64 hv2 = h64[(size_t)__float_as_uint(f2.y) * 16 + cq];
            u64 hv3 = h64[(size_t)__float_as_uint(f3.y) * 16 + cq];
            float w0 = f0.x, w1 = f1.x, w2 = f2.x, w3 = f3.x;
            u32 lo, hi;
            lo = (u32)hv0; hi = (u32)(hv0 >> 32);
            a0 = fmaf(w0, bf2f((u16)(lo & 0xffffu)), a0);
            a1 = fmaf(w0, bf2f((u16)(lo >> 16)),     a1);
            a2 = fmaf(w0, bf2f((u16)(hi & 0xffffu)), a2);
            a3 = fmaf(w0, bf2f((u16)(hi >> 16)),     a3);
            lo = (u32)hv1; hi = (u32)(hv1 >> 32);
            a0 = fmaf(w1, bf2f((u16)(lo & 0xffffu)), a0);
            a1 = fmaf(w1, bf2f((u16)(lo >> 16)),     a1);
            a2 = fmaf(w1, bf2f((u16)(hi & 0xffffu)), a2);
            a3 = fmaf(w1, bf2f((u16)(hi >> 16)),     a3);
            lo = (u32)hv2; hi = (u32)(hv2 >> 32);
            a0 = fmaf(w2, bf2f((u16)(lo & 0xffffu)), a0);
            a1 = fmaf(w2, bf2f((u16)(lo >> 16)),     a1);
            a2 = fmaf(w2, bf2f((u16)(hi & 0xffffu)), a2);
            a3 = fmaf(w2, bf2f((u16)(hi >> 16)),     a3);
            lo = (u32)hv3; hi = (u32)(hv3 >> 32);
            a0 = fmaf(w3, bf2f((u16)(lo & 0xffffu)), a0);
            a1 = fmaf(w3, bf2f((u16)(lo >> 16)),     a1);
            a2 = fmaf(w3, bf2f((u16)(hi & 0xffffu)), a2);
            a3 = fmaf(w3, bf2f((u16)(hi >> 16)),     a3);
        }
    }

    // combine the two edge-halves (partner lane = l32 ^ 16)
    a0 += __shfl_xor(a0, 16);
    a1 += __shfl_xor(a1, 16);
    a2 += __shfl_xor(a2, 16);
    a3 += __shfl_xor(a3, 16);

    if (e2 == 0) {
        *(float4*)(out32 + (size_t)row * C + 4 * cq) = make_float4(a0, a1, a2, a3);
        if (WBF) {
            u32 p0 = (u32)f2bf_rne(a0) | ((u32)f2bf_rne(a1) << 16);
            u32 p1 = (u32)f2bf_rne(a2) | ((u32)f2bf_rne(a3) << 16);
            outbf[(size_t)row * 16 + cq] = (u64)p0 | ((u64)p1 << 32);
        }
    }
}

// --- fused dense epilogue as register-tiled GEMM ---
// out = relu([x | T1 | 2P-x] @ Wcat + b), Wcat = [192][64] (W row-major)
__global__ __launch_bounds__(256) void final_gemm_kernel(
        const float* __restrict__ x,
        const float* __restrict__ T1,
        const float* __restrict__ P,
        const float* __restrict__ W,   // [192][64] row-major
        const float* __restrict__ b,
        float* __restrict__ out, int N) {
    __shared__ float As[16][64];  // [k][node]
    __shared__ float Ws[16][64];  // [k][col]

    int t  = threadIdx.x;
    int tx = t & 15;
    int ty = t >> 4;
    int n0 = blockIdx.x * 64;

    int sn = t >> 2;
    int skb = (t & 3) * 4;

    float acc[4][4];
#pragma unroll
    for (int i = 0; i < 4; i++)
#pragma unroll
        for (int j = 0; j < 4; j++) acc[i][j] = 0.0f;

#pragma unroll 1
    for (int s = 0; s < 12; s++) {
        float4 wv = *(const float4*)(W + s * 1024 + t * 4);
        int nn = n0 + sn;
        float4 av = make_float4(0.f, 0.f, 0.f, 0.f);
        if (nn < N) {
            if (s < 4) {
                av = *(const float4*)(x + (size_t)nn * C + s * 16 + skb);
            } else if (s < 8) {
                av = *(const float4*)(T1 + (size_t)nn * C + (s - 4) * 16 + skb);
            } else {
                float4 pv = *(const float4*)(P + (size_t)nn * C + (s - 8) * 16 + skb);
                float4 xv = *(const float4*)(x + (size_t)nn * C + (s - 8) * 16 + skb);
                av = make_float4(2.0f * pv.x - xv.x, 2.0f * pv.y - xv.y,
                                 2.0f * pv.z - xv.z, 2.0f * pv.w - xv.w);
            }
        }
        __syncthreads();
        {
            int wk = (t * 4) >> 6;
            int wc = (t * 4) & 63;
            *(float4*)&Ws[wk][wc] = wv;
        }
        As[skb + 0][sn] = av.x;
        As[skb + 1][sn] = av.y;
        As[skb + 2][sn] = av.z;
        As[skb + 3][sn] = av.w;
        __syncthreads();

#pragma unroll
        for (int kk = 0; kk < 16; kk++) {
            float4 a4 = *(const float4*)&As[kk][ty * 4];
            float4 w4 = *(const float4*)&Ws[kk][tx * 4];
            float ar[4] = {a4.x, a4.y, a4.z, a4.w};
            float wr[4] = {w4.x, w4.y, w4.z, w4.w};
#pragma unroll
            for (int i = 0; i < 4; i++)
#pragma unroll
                for (int j = 0; j < 4; j++)
                    acc[i][j] = fmaf(ar[i], wr[j], acc[i][j]);
        }
    }

    float4 bv = *(const float4*)(b + tx * 4);
    float br[4] = {bv.x, bv.y, bv.z, bv.w};
#pragma unroll
    for (int i = 0; i < 4; i++) {
        int node = n0 + ty * 4 + i;
        if (node < N) {
            float4 o;
            o.x = fmaxf(acc[i][0] + br[0], 0.0f);
            o.y = fmaxf(acc[i][1] + br[1], 0.0f);
            o.z = fmaxf(acc[i][2] + br[2], 0.0f);
            o.w = fmaxf(acc[i][3] + br[3], 0.0f);
            *(float4*)(out + (size_t)node * C + tx * 4) = o;
        }
    }
}

extern "C" void kernel_launch(void* const* d_in, const int* in_sizes, int n_in,
                              void* d_out, int out_size, void* d_ws, size_t ws_size,
                              hipStream_t stream) {
    const float* x  = (const float*)d_in[0];
    const int*   ei = (const int*)d_in[1];
    const float* ew = (const float*)d_in[2];
    const float* W  = (const float*)d_in[3];
    const float* b  = (const float*)d_in[4];
    float* out = (float*)d_out;

    const int N = in_sizes[0] / C;
    const int E = in_sizes[2];
    const int* row = ei;        // edge_index[0]
    const int* col = ei + E;    // edge_index[1]

    char* ws = (char*)d_ws;
    size_t off = 0;
    auto alloc = [&](size_t bytes) {
        void* p = ws + off;
        off = (off + bytes + 255) & ~(size_t)255;
        return p;
    };
    const int NB = (E + 1023) / 1024;        // histogram/partition blocks
    const int NBUCK = (N + 255) / 256;       // row buckets (196)

    float*  dis    = (float*)alloc((size_t)N * 4);
    int*    rowptr = (int*)alloc((size_t)(N + 1) * 4);
    float2* ewc    = (float2*)alloc((size_t)E * 8);
    u64*    pay    = (u64*)alloc((size_t)E * 8);
    float*  T1     = (float*)alloc((size_t)N * C * 4);
    float*  P      = (float*)alloc((size_t)N * C * 4);
    u32*    hoff   = (u32*)alloc((size_t)NB * 256 * 4);
    u32*    T      = (u32*)alloc((size_t)256 * 4);
    u32*    Tpre   = (u32*)alloc((size_t)257 * 4);
    u32*    done   = (u32*)alloc((size_t)256);
    u16*    xh     = (u16*)alloc((size_t)N * C * 2);
    u16*    T1h    = (u16*)alloc((size_t)N * C * 2);

    const int B = 256;
    int total4 = N * C / 4;

    p1hist_kernel<<<NB, B, 0, stream>>>(row, hoff, x, xh, done, E, NB, total4, NB * B);
    scanAB_kernel<<<256, B, 0, stream>>>(hoff, T, Tpre, rowptr, done, N, NB);
    p1scatter_kernel<<<NB, B, 0, stream>>>(row, col, ew, hoff, Tpre, pay, E);
    p2_kernel<<<NBUCK, B, 0, stream>>>(pay, Tpre, rowptr, dis, ewc, N);

    int spmm_blocks = (N + 7) / 8;           // 8 rows per block (half-wave per row)
    spmm_kernel<1><<<spmm_blocks, B, 0, stream>>>(rowptr, ewc, dis, (const u64*)xh,
                                                  T1, (u64*)T1h, N);
    spmm_kernel<0><<<spmm_blocks, B, 0, stream>>>(rowptr, ewc, dis, (const u64*)T1h,
                                                  P, (u64*)nullptr, N);

    final_gemm_kernel<<<(N + 63) / 64, B, 0, stream>>>(x, T1, P, W, b, out, N);
}

// Round 7
// 188.786 us; speedup vs baseline: 1.1033x; 1.0065x over previous
//
#include <hip/hip_runtime.h>
#include <hip/hip_bf16.h>

#define C 64   // C_IN == C_OUT == 64

typedef unsigned short u16;
typedef unsigned int u32;
typedef unsigned long long u64;

__device__ __forceinline__ u16 f2bf_rne(float v) {
    unsigned u = __float_as_uint(v);
    u += 0x7FFFu + ((u >> 16) & 1u);
    return (u16)(u >> 16);
}
__device__ __forceinline__ float bf2f(u16 u) {
    return __uint_as_float((unsigned)u << 16);
}

// ============================================================================
// Atomic-free CSR build: MSD bucket sort by row>>8 (256 buckets), then
// per-bucket counting sort by row&255. No global atomics in the hot path.
// ============================================================================

// --- P1 hist: per-block 256-bin LDS histogram of row>>8; fused x->bf16;
// zeroes the scanAB done-ticket. ---
__global__ __launch_bounds__(256) void p1hist_kernel(const int* __restrict__ row,
                                                     u32* __restrict__ hoff,  // [NB][256]
                                                     const float* __restrict__ x,
                                                     u16* __restrict__ xh,
                                                     u32* __restrict__ done,
                                                     int E, int NB, int total4, int nthreads) {
    __shared__ u32 h[256];
    int t = threadIdx.x;
    int b = blockIdx.x;
    if (b == 0 && t == 0) *done = 0;
    h[t] = 0;
    __syncthreads();
    int base = b * 1024;
#pragma unroll
    for (int u = 0; u < 4; u++) {
        int e = base + u * 256 + t;
        if (e < E) {
            int r = row[e];
            atomicAdd(&h[r >> 8], 1u);
        }
    }
    __syncthreads();
    hoff[(size_t)b * 256 + t] = h[t];   // block-major, coalesced

    // fused x -> bf16 convert (grid-stride)
    int gtid = b * 256 + t;
    for (int i = gtid; i < total4; i += nthreads) {
        float4 v = *(const float4*)(x + (size_t)i * 4);
        ushort4 o;
        o.x = f2bf_rne(v.x); o.y = f2bf_rne(v.y);
        o.z = f2bf_rne(v.z); o.w = f2bf_rne(v.w);
        *(ushort4*)(xh + (size_t)i * 4) = o;
    }
}

// --- scanAB (fused): block d scans hoff[.][d] over blocks (exclusive,
// in-place), T[d] = total. Last block (device ticket) scans T -> Tpre. ---
__global__ __launch_bounds__(256) void scanAB_kernel(u32* __restrict__ hoff,
                                                     u32* __restrict__ T,
                                                     u32* __restrict__ Tpre,
                                                     int* __restrict__ rowptr,
                                                     u32* __restrict__ done,
                                                     int N, int NB) {
    __shared__ u32 s[256];
    __shared__ u32 lastFlag;
    int t = threadIdx.x;
    int d = blockIdx.x;
    u32 carry = 0;
    int nchunk = (NB + 255) / 256;
    for (int ch = 0; ch < nchunk; ch++) {
        int idx = ch * 256 + t;
        u32 v = (idx < NB) ? hoff[(size_t)idx * 256 + d] : 0;
        s[t] = v;
        __syncthreads();
        for (int off = 1; off < 256; off <<= 1) {
            u32 u = (t >= off) ? s[t - off] : 0;
            __syncthreads();
            s[t] += u;
            __syncthreads();
        }
        if (idx < NB) hoff[(size_t)idx * 256 + d] = carry + s[t] - v;  // exclusive
        u32 tot = s[255];
        __syncthreads();
        carry += tot;
    }
    if (t == 0) T[d] = carry;
    __threadfence();                      // release T[d]
    if (t == 0) {
        u32 tk = atomicAdd(done, 1u);
        lastFlag = (tk == 255u) ? 1u : 0u;
    }
    __syncthreads();
    if (lastFlag) {
        __threadfence();                  // acquire all T[]
        u32 v = T[t];
        s[t] = v;
        __syncthreads();
        for (int off = 1; off < 256; off <<= 1) {
            u32 u = (t >= off) ? s[t - off] : 0;
            __syncthreads();
            s[t] += u;
            __syncthreads();
        }
        Tpre[t] = s[t] - v;
        if (t == 255) {
            Tpre[256] = s[255];
            rowptr[N] = (int)s[255];
        }
    }
}

// --- P1 scatter: place edges into their row>>8 bucket. Within-bucket order
// arbitrary (LDS returning atomics) — legal for an MSD pass. Payload packs
// (row<<16)|col in high 32 bits, ew bits in low 32. ---
__global__ __launch_bounds__(256) void p1scatter_kernel(const int* __restrict__ row,
                                                        const int* __restrict__ col,
                                                        const float* __restrict__ ew,
                                                        const u32* __restrict__ hoff, // [NB][256] excl
                                                        const u32* __restrict__ Tpre,
                                                        u64* __restrict__ pay,
                                                        int E) {
    __shared__ u32 cur[256];
    int t = threadIdx.x;
    int b = blockIdx.x;
    cur[t] = Tpre[t] + hoff[(size_t)b * 256 + t];
    __syncthreads();
    int base = b * 1024;
#pragma unroll
    for (int u = 0; u < 4; u++) {
        int e = base + u * 256 + t;
        if (e < E) {
            u32 r = (u32)row[e];
            u32 c = (u32)col[e];
            u32 rc = (r << 16) | c;
            u32 pos = atomicAdd(&cur[r >> 8], 1u);
            pay[pos] = ((u64)rc << 32) | (u64)__float_as_uint(ew[e]);
        }
    }
}

// --- P2: per-bucket counting sort by row&255 into final CSR; writes rowptr
// for this bucket's 256 rows, deg sums (LDS f32 atomics) -> dis.
// ewc stores (raw ew, pure col); pass-1 SpMM normalizes and writes back. ---
__global__ __launch_bounds__(256) void p2_kernel(const u64* __restrict__ pay,
                                                 const u32* __restrict__ Tpre,
                                                 int* __restrict__ rowptr,
                                                 float* __restrict__ dis,
                                                 float2* __restrict__ ewc,
                                                 int N) {
    __shared__ u32 h[256];
    __shared__ u32 s[256];
    __shared__ u32 cur[256];
    __shared__ float dsum[256];
    int t = threadIdx.x;
    int bk = blockIdx.x;
    u32 base = Tpre[bk];
    u32 cnt = Tpre[bk + 1] - base;

    h[t] = 0;
    dsum[t] = 0.0f;
    __syncthreads();
    for (u32 j = t; j < cnt; j += 256) {
        u64 v = pay[base + j];
        u32 lr = (u32)(v >> 48) & 255u;   // row & 255 (row>>8 == bk here)
        atomicAdd(&h[lr], 1u);
    }
    __syncthreads();
    // exclusive scan of h
    u32 hv = h[t];
    s[t] = hv;
    __syncthreads();
    for (int off = 1; off < 256; off <<= 1) {
        u32 u = (t >= off) ? s[t - off] : 0;
        __syncthreads();
        s[t] += u;
        __syncthreads();
    }
    u32 p = s[t] - hv;   // exclusive
    int r = bk * 256 + t;
    if (r < N) rowptr[r] = (int)(base + p);
    cur[t] = base + p;
    __syncthreads();
    for (u32 j = t; j < cnt; j += 256) {
        u64 v = pay[base + j];
        u32 rc = (u32)(v >> 32);
        u32 lr = (rc >> 16) & 255u;
        float w = __uint_as_float((u32)v);
        u32 pos = atomicAdd(&cur[lr], 1u);
        ewc[pos] = make_float2(w, __uint_as_float(rc & 0xffffu));  // raw ew, pure col
        atomicAdd(&dsum[lr], w);
    }
    __syncthreads();
    if (r < N) {
        float dv = dsum[t];
        dis[r] = (dv > 0.0f) ? rsqrtf(dv) : 0.0f;
    }
}

// ============================================================================
// CSR SpMM: half-wave per row (2 rows/wave), u64 (4-channel) gathers, LDS
// edge staging. NORM=1 (pass 1): normalize w = -dis[r]*ew*dis[c], write the
// normalized edge back to ewc (coalesced) for pass 2, and emit bf16 output.
// NORM=0 (pass 2): consume normalized ewc directly — NO dis gathers on the
// critical path (r6 lesson: dependent scattered loads cost >> streaming
// writeback). High grid (N/8 blocks) — gather latency hidden by TLP.
// ============================================================================
template <int NORM>
__global__ __launch_bounds__(256) void spmm_kernel(
        const int* __restrict__ rowptr,
        float2* __restrict__ ewc,
        const float* __restrict__ dis,
        const u64* __restrict__ h64,        // bf16 [N][64] viewed as [N][16] u64
        float* __restrict__ out32,          // fp32 [N][C]
        u64* __restrict__ outbf,            // bf16 [N][64] viewed as [N][16] u64
        int N) {
    __shared__ float2 eds[8][32];           // per half-wave staging (2 KB)

    int tid  = threadIdx.x;
    int hw   = tid >> 5;                    // half-wave slot in block 0..7
    int l32  = tid & 31;                    // lane within half
    int e2   = l32 >> 4;                    // edge selector within pair
    int cq   = l32 & 15;                    // channel quad (4 bf16 via u64)

    int row = blockIdx.x * 8 + hw;
    if (row >= N) return;

    int beg = rowptr[row];
    int end = rowptr[row + 1];
    float disr = NORM ? dis[row] : 0.0f;

    float a0 = 0.f, a1 = 0.f, a2 = 0.f, a3 = 0.f;

    for (int base = beg; base < end; base += 32) {
        int idx = base + l32;
        bool valid = idx < end;
        // zero-pad: w=0, col=0 -> harmless gather of row 0
        float2 ed = valid ? ewc[idx] : make_float2(0.0f, __uint_as_float(0));
        if (NORM) {
            u32 c = __float_as_uint(ed.y);
            ed.x = -disr * ed.x * dis[c];
            if (valid) ewc[idx] = ed;       // coalesced writeback for pass 2
        }
        eds[hw][l32] = ed;
        int cnt = end - base; if (cnt > 32) cnt = 32;
        int cnt8 = (cnt + 7) & ~7;          // padded slots are zeros
        for (int j = 0; j < cnt8; j += 8) {
            float2 f0 = eds[hw][j + e2];
            float2 f1 = eds[hw][j + 2 + e2];
            float2 f2 = eds[hw][j + 4 + e2];
            float2 f3 = eds[hw][j + 6 + e2];
            u64 hv0 = h64[(size_t)__float_as_uint(f0.y) * 16 + cq];
            u64 hv1 = h64[(size_t)__float_as_uint(f1.y) * 16 + cq];
            u64 hv2 = h64[(size_t)__float_as_uint(f2.y) * 16 + cq];
            u64 hv3 = h64[(size_t)__float_as_uint(f3.y) * 16 + cq];
            float w0 = f0.x, w1 = f1.x, w2 = f2.x, w3 = f3.x;
            u32 lo, hi;
            lo = (u32)hv0; hi = (u32)(hv0 >> 32);
            a0 = fmaf(w0, bf2f((u16)(lo & 0xffffu)), a0);
            a1 = fmaf(w0, bf2f((u16)(lo >> 16)),     a1);
            a2 = fmaf(w0, bf2f((u16)(hi & 0xffffu)), a2);
            a3 = fmaf(w0, bf2f((u16)(hi >> 16)),     a3);
            lo = (u32)hv1; hi = (u32)(hv1 >> 32);
            a0 = fmaf(w1, bf2f((u16)(lo & 0xffffu)), a0);
            a1 = fmaf(w1, bf2f((u16)(lo >> 16)),     a1);
            a2 = fmaf(w1, bf2f((u16)(hi & 0xffffu)), a2);
            a3 = fmaf(w1, bf2f((u16)(hi >> 16)),     a3);
            lo = (u32)hv2; hi = (u32)(hv2 >> 32);
            a0 = fmaf(w2, bf2f((u16)(lo & 0xffffu)), a0);
            a1 = fmaf(w2, bf2f((u16)(lo >> 16)),     a1);
            a2 = fmaf(w2, bf2f((u16)(hi & 0xffffu)), a2);
            a3 = fmaf(w2, bf2f((u16)(hi >> 16)),     a3);
            lo = (u32)hv3; hi = (u32)(hv3 >> 32);
            a0 = fmaf(w3, bf2f((u16)(lo & 0xffffu)), a0);
            a1 = fmaf(w3, bf2f((u16)(lo >> 16)),     a1);
            a2 = fmaf(w3, bf2f((u16)(hi & 0xffffu)), a2);
            a3 = fmaf(w3, bf2f((u16)(hi >> 16)),     a3);
        }
    }

    // combine the two edge-halves (partner lane = l32 ^ 16)
    a0 += __shfl_xor(a0, 16);
    a1 += __shfl_xor(a1, 16);
    a2 += __shfl_xor(a2, 16);
    a3 += __shfl_xor(a3, 16);

    if (e2 == 0) {
        *(float4*)(out32 + (size_t)row * C + 4 * cq) = make_float4(a0, a1, a2, a3);
        if (NORM) {
            u32 p0 = (u32)f2bf_rne(a0) | ((u32)f2bf_rne(a1) << 16);
            u32 p1 = (u32)f2bf_rne(a2) | ((u32)f2bf_rne(a3) << 16);
            outbf[(size_t)row * 16 + cq] = (u64)p0 | ((u64)p1 << 32);
        }
    }
}

// --- fused dense epilogue as register-tiled GEMM ---
// out = relu([x | T1 | 2P-x] @ Wcat + b), Wcat = [192][64] (W row-major)
__global__ __launch_bounds__(256) void final_gemm_kernel(
        const float* __restrict__ x,
        const float* __restrict__ T1,
        const float* __restrict__ P,
        const float* __restrict__ W,   // [192][64] row-major
        const float* __restrict__ b,
        float* __restrict__ out, int N) {
    __shared__ float As[16][64];  // [k][node]
    __shared__ float Ws[16][64];  // [k][col]

    int t  = threadIdx.x;
    int tx = t & 15;
    int ty = t >> 4;
    int n0 = blockIdx.x * 64;

    int sn = t >> 2;
    int skb = (t & 3) * 4;

    float acc[4][4];
#pragma unroll
    for (int i = 0; i < 4; i++)
#pragma unroll
        for (int j = 0; j < 4; j++) acc[i][j] = 0.0f;

#pragma unroll 1
    for (int s = 0; s < 12; s++) {
        float4 wv = *(const float4*)(W + s * 1024 + t * 4);
        int nn = n0 + sn;
        float4 av = make_float4(0.f, 0.f, 0.f, 0.f);
        if (nn < N) {
            if (s < 4) {
                av = *(const float4*)(x + (size_t)nn * C + s * 16 + skb);
            } else if (s < 8) {
                av = *(const float4*)(T1 + (size_t)nn * C + (s - 4) * 16 + skb);
            } else {
                float4 pv = *(const float4*)(P + (size_t)nn * C + (s - 8) * 16 + skb);
                float4 xv = *(const float4*)(x + (size_t)nn * C + (s - 8) * 16 + skb);
                av = make_float4(2.0f * pv.x - xv.x, 2.0f * pv.y - xv.y,
                                 2.0f * pv.z - xv.z, 2.0f * pv.w - xv.w);
            }
        }
        __syncthreads();
        {
            int wk = (t * 4) >> 6;
            int wc = (t * 4) & 63;
            *(float4*)&Ws[wk][wc] = wv;
        }
        As[skb + 0][sn] = av.x;
        As[skb + 1][sn] = av.y;
        As[skb + 2][sn] = av.z;
        As[skb + 3][sn] = av.w;
        __syncthreads();

#pragma unroll
        for (int kk = 0; kk < 16; kk++) {
            float4 a4 = *(const float4*)&As[kk][ty * 4];
            float4 w4 = *(const float4*)&Ws[kk][tx * 4];
            float ar[4] = {a4.x, a4.y, a4.z, a4.w};
            float wr[4] = {w4.x, w4.y, w4.z, w4.w};
#pragma unroll
            for (int i = 0; i < 4; i++)
#pragma unroll
                for (int j = 0; j < 4; j++)
                    acc[i][j] = fmaf(ar[i], wr[j], acc[i][j]);
        }
    }

    float4 bv = *(const float4*)(b + tx * 4);
    float br[4] = {bv.x, bv.y, bv.z, bv.w};
#pragma unroll
    for (int i = 0; i < 4; i++) {
        int node = n0 + ty * 4 + i;
        if (node < N) {
            float4 o;
            o.x = fmaxf(acc[i][0] + br[0], 0.0f);
            o.y = fmaxf(acc[i][1] + br[1], 0.0f);
            o.z = fmaxf(acc[i][2] + br[2], 0.0f);
            o.w = fmaxf(acc[i][3] + br[3], 0.0f);
            *(float4*)(out + (size_t)node * C + tx * 4) = o;
        }
    }
}

extern "C" void kernel_launch(void* const* d_in, const int* in_sizes, int n_in,
                              void* d_out, int out_size, void* d_ws, size_t ws_size,
                              hipStream_t stream) {
    const float* x  = (const float*)d_in[0];
    const int*   ei = (const int*)d_in[1];
    const float* ew = (const float*)d_in[2];
    const float* W  = (const float*)d_in[3];
    const float* b  = (const float*)d_in[4];
    float* out = (float*)d_out;

    const int N = in_sizes[0] / C;
    const int E = in_sizes[2];
    const int* row = ei;        // edge_index[0]
    const int* col = ei + E;    // edge_index[1]

    char* ws = (char*)d_ws;
    size_t off = 0;
    auto alloc = [&](size_t bytes) {
        void* p = ws + off;
        off = (off + bytes + 255) & ~(size_t)255;
        return p;
    };
    const int NB = (E + 1023) / 1024;        // histogram/partition blocks
    const int NBUCK = (N + 255) / 256;       // row buckets (196)

    float*  dis    = (float*)alloc((size_t)N * 4);
    int*    rowptr = (int*)alloc((size_t)(N + 1) * 4);
    float2* ewc    = (float2*)alloc((size_t)E * 8);
    u64*    pay    = (u64*)alloc((size_t)E * 8);
    float*  T1     = (float*)alloc((size_t)N * C * 4);
    float*  P      = (float*)alloc((size_t)N * C * 4);
    u32*    hoff   = (u32*)alloc((size_t)NB * 256 * 4);
    u32*    T      = (u32*)alloc((size_t)256 * 4);
    u32*    Tpre   = (u32*)alloc((size_t)257 * 4);
    u32*    done   = (u32*)alloc((size_t)256);
    u16*    xh     = (u16*)alloc((size_t)N * C * 2);
    u16*    T1h    = (u16*)alloc((size_t)N * C * 2);

    const int B = 256;
    int total4 = N * C / 4;

    p1hist_kernel<<<NB, B, 0, stream>>>(row, hoff, x, xh, done, E, NB, total4, NB * B);
    scanAB_kernel<<<256, B, 0, stream>>>(hoff, T, Tpre, rowptr, done, N, NB);
    p1scatter_kernel<<<NB, B, 0, stream>>>(row, col, ew, hoff, Tpre, pay, E);
    p2_kernel<<<NBUCK, B, 0, stream>>>(pay, Tpre, rowptr, dis, ewc, N);

    int spmm_blocks = (N + 7) / 8;           // 8 rows per block (half-wave per row)
    spmm_kernel<1><<<spmm_blocks, B, 0, stream>>>(rowptr, ewc, dis, (const u64*)xh,
                                                  T1, (u64*)T1h, N);
    spmm_kernel<0><<<spmm_blocks, B, 0, stream>>>(rowptr, ewc, dis, (const u64*)T1h,
                                                  P, (u64*)nullptr, N);

    final_gemm_kernel<<<(N + 63) / 64, B, 0, stream>>>(x, T1, P, W, b, out, N);
}